// Round 3
// baseline (502.041 us; speedup 1.0000x reference)
//
#include <hip/hip_runtime.h>
#include <hip/hip_bf16.h>
#include <stdint.h>

// CommNetActor: B=8192, A=64 agents, OBS=128, D=64, NACT=32
//
// v3: TRANSPOSED formulation. Per sample compute G = H^T (feat x agent):
//   G' = Wcat^T . [G ; Stil (x) 1] + b (x) 1,   Stil = S/64
// so weights are the A-operand (frags identical for every wave, L1/L2-hot),
// data is the B-operand. C-layout of G has consecutive FEATS in the 4 regs
// -> epilogue is 16 ds_write_b64 (vs 64 ds_write_u16 in v2) and next-layer
// B-frags are 8 ds_read_b128 from [agent][feat] rows.
// Comm layers are LINEAR -> Stil' = Stil . Wsum + b  (Wsum = Wtop + 63/64 Wbot)
// computed via 8 extra MFMAs reusing the Stil B-frags; the 64-lane butterfly
// reduction is needed only ONCE (after the sigmoid).

#define BATCHN 8192

typedef __attribute__((ext_vector_type(8))) short short8;   // 8 bf16
typedef __attribute__((ext_vector_type(4))) float floatx4;  // MFMA acc

__device__ __forceinline__ unsigned short f2b(float f) {
    union { float f; uint32_t u; } v; v.f = f;
    uint32_t r = v.u + 0x7FFFu + ((v.u >> 16) & 1u);
    return (unsigned short)(r >> 16);
}

__device__ __forceinline__ uint32_t pk2(float x, float y) {
    float2 t; t.x = x; t.y = y;
    __hip_bfloat162 h = __float22bfloat162_rn(t);
    union { __hip_bfloat162 h; uint32_t u; } c; c.h = h;
    return c.u;
}

// ---- ws layout (u16 units) ----
#define U16_WENC 0         // WencT [64 f][128 k]
#define U16_WCAT 8192      // WcatT [4 l][64 f][128 k]
#define U16_WSUM 40960     // WsumT [4 l][64 f][64 k]
#define U16_WDEC 57344     // WdecT [32 n][4096 k]
#define U16_H4   188416    // H4    [8192][4096]

// ---------------- prep: transpose + bf16-convert weights ----------------
__global__ __launch_bounds__(256) void prep_kernel(
    const float* __restrict__ Wenc,
    const float* __restrict__ W1, const float* __restrict__ W2,
    const float* __restrict__ W3, const float* __restrict__ W4,
    const float* __restrict__ Wdec,
    unsigned short* __restrict__ ws)
{
    int tid = blockIdx.x * 256 + threadIdx.x;   // grid covers exactly 188416
    const float* WL[4] = {W1, W2, W3, W4};
    if (tid < 8192) {
        int n = tid >> 7, k = tid & 127;
        ws[U16_WENC + n*128 + k] = f2b(Wenc[k*64 + n]);
    } else if (tid < 40960) {
        int e = tid - 8192;
        int l = e >> 13, r = e & 8191;
        int n = r >> 7, k = r & 127;
        const float* W = WL[l];
        float v = W[k*64 + n];                       // k<64: Wtop, k>=64: Wbot
        if (k < 64) v -= W[(k+64)*64 + n] * (1.0f/64.0f);
        ws[U16_WCAT + l*8192 + n*128 + k] = f2b(v);
    } else if (tid < 57344) {
        int e = tid - 40960;
        int l = e >> 12, r = e & 4095;
        int f = r >> 6, k = r & 63;
        const float* W = WL[l];
        float v = W[k*64 + f] + W[(k+64)*64 + f] * (63.0f/64.0f);
        ws[U16_WSUM + l*4096 + f*64 + k] = f2b(v);
    } else {
        int e = tid - 57344;                         // 0..131071
        int n = e >> 12, k = e & 4095;
        ws[U16_WDEC + n*4096 + k] = f2b(Wdec[k*32 + n]);
    }
}

// ---------------- fused encoder + 4 comm layers (wave-per-sample) ----------------
__global__ __launch_bounds__(256, 3) void fused3_kernel(
    const float* __restrict__ O,
    const unsigned short* __restrict__ WencT,
    const unsigned short* __restrict__ WcatT,
    const unsigned short* __restrict__ WsumT,
    const float* __restrict__ b_enc,
    const float* __restrict__ b1, const float* __restrict__ b2,
    const float* __restrict__ b3, const float* __restrict__ b4,
    unsigned short* __restrict__ H4out)
{
    __shared__ unsigned short sG[4][64*72];   // per-wave G, [agent][feat] pad72
    __shared__ unsigned short sS[4][64];      // per-wave Stil row (bf16)

    const int t = threadIdx.x, lane = t & 63, w = t >> 6;
    const int m = lane & 15, q = lane >> 4;
    const int b = blockIdx.x * 4 + w;
    unsigned short* myG = sG[w];
    unsigned short* myS = sS[w];

    floatx4 acc[4][4];   // [ft][at]: G[feat=ft*16+q*4+r][agent=at*16+m]
    floatx4 bb[4];       // bias per ft (per-reg = per-feat)

    // ---- encoder: G0 = sigmoid(Wenc^T . O^T + b (x) 1), K=128 ----
    #pragma unroll
    for (int ft = 0; ft < 4; ft++) {
        float4 bv = *(const float4*)(b_enc + ft*16 + q*4);
        bb[ft] = (floatx4){bv.x, bv.y, bv.z, bv.w};
    }
    #pragma unroll
    for (int ft = 0; ft < 4; ft++)
        #pragma unroll
        for (int at = 0; at < 4; at++)
            acc[ft][at] = bb[ft];

    const float* Ob = O + (size_t)b * 8192;
    #pragma unroll
    for (int s = 0; s < 4; s++) {
        short8 Wf[4], Bf[4];
        #pragma unroll
        for (int ft = 0; ft < 4; ft++)
            Wf[ft] = *(const short8*)(WencT + (ft*16+m)*128 + s*32 + q*8);
        #pragma unroll
        for (int at = 0; at < 4; at++) {
            const float* pr = Ob + (at*16+m)*128 + s*32 + q*8;
            float4 f0 = *(const float4*)pr;
            float4 f1 = *(const float4*)(pr + 4);
            uint32_t* pa = (uint32_t*)&Bf[at];
            pa[0] = pk2(f0.x, f0.y); pa[1] = pk2(f0.z, f0.w);
            pa[2] = pk2(f1.x, f1.y); pa[3] = pk2(f1.z, f1.w);
        }
        #pragma unroll
        for (int ft = 0; ft < 4; ft++)
            #pragma unroll
            for (int at = 0; at < 4; at++)
                acc[ft][at] = __builtin_amdgcn_mfma_f32_16x16x32_bf16(Wf[ft], Bf[at], acc[ft][at], 0, 0, 0);
    }
    #pragma unroll
    for (int ft = 0; ft < 4; ft++)
        #pragma unroll
        for (int at = 0; at < 4; at++)
            #pragma unroll
            for (int r = 0; r < 4; r++)
                acc[ft][at][r] = 1.0f / (1.0f + __expf(-acc[ft][at][r]));

    // ---- S0 butterfly (once; sigmoid is the only nonlinearity) ----
    #pragma unroll
    for (int ft = 0; ft < 4; ft++) {
        float tr[4];
        #pragma unroll
        for (int r = 0; r < 4; r++)
            tr[r] = acc[ft][0][r] + acc[ft][1][r] + acc[ft][2][r] + acc[ft][3][r];
        #pragma unroll
        for (int msk = 1; msk <= 8; msk <<= 1)
            #pragma unroll
            for (int r = 0; r < 4; r++)
                tr[r] += __shfl_xor(tr[r], msk, 64);
        uint2 d;
        d.x = pk2(tr[0] * (1.0f/64.0f), tr[1] * (1.0f/64.0f));
        d.y = pk2(tr[2] * (1.0f/64.0f), tr[3] * (1.0f/64.0f));
        if (m == 0) *(uint2*)&myS[ft*16 + q*4] = d;
    }
    // ---- G0 -> LDS [agent][feat] (vectorized b64) ----
    #pragma unroll
    for (int ft = 0; ft < 4; ft++)
        #pragma unroll
        for (int at = 0; at < 4; at++) {
            uint2 d;
            d.x = pk2(acc[ft][at][0], acc[ft][at][1]);
            d.y = pk2(acc[ft][at][2], acc[ft][at][3]);
            *(uint2*)&myG[(at*16+m)*72 + ft*16 + q*4] = d;
        }

    // ---- 4 comm layers ----
    const float* bs_[4] = {b1, b2, b3, b4};
    #pragma unroll
    for (int l = 0; l < 4; l++) {
        const unsigned short* Wl  = WcatT + l*8192;
        const unsigned short* Wsl = WsumT + l*4096;
        const float* bp = bs_[l];
        #pragma unroll
        for (int ft = 0; ft < 4; ft++) {
            float4 bv = *(const float4*)(bp + ft*16 + q*4);
            bb[ft] = (floatx4){bv.x, bv.y, bv.z, bv.w};
        }
        short8 Sf[2];
        #pragma unroll
        for (int s2 = 0; s2 < 2; s2++)
            Sf[s2] = *(const short8*)&myS[s2*32 + q*8];

        #pragma unroll
        for (int ft = 0; ft < 4; ft++)
            #pragma unroll
            for (int at = 0; at < 4; at++)
                acc[ft][at] = bb[ft];

        // k = 0..63: B from G (LDS rows)
        #pragma unroll
        for (int s2 = 0; s2 < 2; s2++) {
            short8 Wf[4], Gf[4];
            #pragma unroll
            for (int ft = 0; ft < 4; ft++)
                Wf[ft] = *(const short8*)(Wl + (ft*16+m)*128 + s2*32 + q*8);
            #pragma unroll
            for (int at = 0; at < 4; at++)
                Gf[at] = *(const short8*)&myG[(at*16+m)*72 + s2*32 + q*8];
            #pragma unroll
            for (int ft = 0; ft < 4; ft++)
                #pragma unroll
                for (int at = 0; at < 4; at++)
                    acc[ft][at] = __builtin_amdgcn_mfma_f32_16x16x32_bf16(Wf[ft], Gf[at], acc[ft][at], 0, 0, 0);
        }
        // k = 64..127: B rows are Stil broadcast across agents
        #pragma unroll
        for (int s2 = 0; s2 < 2; s2++) {
            short8 Wf[4];
            #pragma unroll
            for (int ft = 0; ft < 4; ft++)
                Wf[ft] = *(const short8*)(Wl + (ft*16+m)*128 + (2+s2)*32 + q*8);
            #pragma unroll
            for (int ft = 0; ft < 4; ft++)
                #pragma unroll
                for (int at = 0; at < 4; at++)
                    acc[ft][at] = __builtin_amdgcn_mfma_f32_16x16x32_bf16(Wf[ft], Sf[s2], acc[ft][at], 0, 0, 0);
        }

        if (l < 3) {
            // Stil' = Stil . Wsum + b via MFMA (reuse Sf frags; all cols equal)
            floatx4 sacc[4];
            #pragma unroll
            for (int ft = 0; ft < 4; ft++) sacc[ft] = (floatx4){0.f, 0.f, 0.f, 0.f};
            #pragma unroll
            for (int s2 = 0; s2 < 2; s2++) {
                #pragma unroll
                for (int ft = 0; ft < 4; ft++) {
                    short8 Wsf = *(const short8*)(Wsl + (ft*16+m)*64 + s2*32 + q*8);
                    sacc[ft] = __builtin_amdgcn_mfma_f32_16x16x32_bf16(Wsf, Sf[s2], sacc[ft], 0, 0, 0);
                }
            }
            #pragma unroll
            for (int ft = 0; ft < 4; ft++) {
                uint2 d;
                d.x = pk2(sacc[ft][0] + bb[ft][0], sacc[ft][1] + bb[ft][1]);
                d.y = pk2(sacc[ft][2] + bb[ft][2], sacc[ft][3] + bb[ft][3]);
                if (m == 0) *(uint2*)&myS[ft*16 + q*4] = d;
            }
            // G' -> LDS (in-order per-wave DS ops: reads of this layer are done)
            #pragma unroll
            for (int ft = 0; ft < 4; ft++)
                #pragma unroll
                for (int at = 0; at < 4; at++) {
                    uint2 d;
                    d.x = pk2(acc[ft][at][0], acc[ft][at][1]);
                    d.y = pk2(acc[ft][at][2], acc[ft][at][3]);
                    *(uint2*)&myG[(at*16+m)*72 + ft*16 + q*4] = d;
                }
        } else {
            // final store: H4[sample][agent][feat] bf16, b64 per tile
            unsigned short* Hb = H4out + (size_t)b * 4096;
            #pragma unroll
            for (int ft = 0; ft < 4; ft++)
                #pragma unroll
                for (int at = 0; at < 4; at++) {
                    uint2 d;
                    d.x = pk2(acc[ft][at][0], acc[ft][at][1]);
                    d.y = pk2(acc[ft][at][2], acc[ft][at][3]);
                    *(uint2*)(Hb + (at*16+m)*64 + ft*16 + q*4) = d;
                }
        }
    }
}

// ---------------- decoder: out = Hf @ Wdec + b_dec ----------------
// M=8192, N=32, K=4096; K-split x8, fp32 atomicAdd epilogue (out pre-zeroed).
__global__ __launch_bounds__(256) void dec_kernel(
    const unsigned short* __restrict__ Hf,     // [8192][4096] bf16
    const unsigned short* __restrict__ WdecT,  // [32][4096] bf16
    const float* __restrict__ b_dec,
    float* __restrict__ out)                   // [8192][32] fp32
{
    int gt = blockIdx.x * 256 + threadIdx.x;
    int wave = gt >> 6;          // 0..4095
    int lane = gt & 63;
    int rb = wave >> 3;          // rows [rb*16, rb*16+16)
    int kc = wave & 7;           // K chunk [kc*512, +512)
    int m = lane & 15, q = lane >> 4;

    const unsigned short* aP  = Hf    + (size_t)(rb*16 + m)*4096 + kc*512 + q*8;
    const unsigned short* bP0 = WdecT + (size_t)m*4096        + kc*512 + q*8;
    const unsigned short* bP1 = WdecT + (size_t)(16 + m)*4096 + kc*512 + q*8;

    floatx4 a0 = {0.f, 0.f, 0.f, 0.f}, a1 = {0.f, 0.f, 0.f, 0.f};
    #pragma unroll 4
    for (int s = 0; s < 16; s++) {
        short8 av  = *(const short8*)(aP  + s*32);
        short8 b0v = *(const short8*)(bP0 + s*32);
        short8 b1v = *(const short8*)(bP1 + s*32);
        a0 = __builtin_amdgcn_mfma_f32_16x16x32_bf16(av, b0v, a0, 0, 0, 0);
        a1 = __builtin_amdgcn_mfma_f32_16x16x32_bf16(av, b1v, a1, 0, 0, 0);
    }
    float bias0 = (kc == 0) ? b_dec[m]      : 0.0f;
    float bias1 = (kc == 0) ? b_dec[16 + m] : 0.0f;
    #pragma unroll
    for (int r = 0; r < 4; r++) {
        int row = rb*16 + q*4 + r;
        atomicAdd(&out[row*32 + m],      a0[r] + bias0);
        atomicAdd(&out[row*32 + 16 + m], a1[r] + bias1);
    }
}

extern "C" void kernel_launch(void* const* d_in, const int* in_sizes, int n_in,
                              void* d_out, int out_size, void* d_ws, size_t ws_size,
                              hipStream_t stream)
{
    const float* O    = (const float*)d_in[0];
    const float* Wenc = (const float*)d_in[1];
    const float* benc = (const float*)d_in[2];
    const float* W1   = (const float*)d_in[3];
    const float* b1   = (const float*)d_in[4];
    const float* W2   = (const float*)d_in[5];
    const float* b2   = (const float*)d_in[6];
    const float* W3   = (const float*)d_in[7];
    const float* b3   = (const float*)d_in[8];
    const float* W4   = (const float*)d_in[9];
    const float* b4   = (const float*)d_in[10];
    const float* Wdec = (const float*)d_in[11];
    const float* bdec = (const float*)d_in[12];
    float* out = (float*)d_out;
    unsigned short* ws = (unsigned short*)d_ws;

    hipMemsetAsync(d_out, 0, (size_t)out_size * sizeof(float), stream);
    prep_kernel<<<736, 256, 0, stream>>>(Wenc, W1, W2, W3, W4, Wdec, ws);
    fused3_kernel<<<2048, 256, 0, stream>>>(O, ws + U16_WENC, ws + U16_WCAT,
                                            ws + U16_WSUM,
                                            benc, b1, b2, b3, b4, ws + U16_H4);
    dec_kernel<<<1024, 256, 0, stream>>>(ws + U16_H4, ws + U16_WDEC, bdec, out);
}

// Round 4
// 499.903 us; speedup vs baseline: 1.0043x; 1.0043x over previous
//
#include <hip/hip_runtime.h>
#include <hip/hip_bf16.h>
#include <stdint.h>

// CommNetActor: B=8192, A=64 agents, OBS=128, D=64, NACT=32
//
// v4: transposed formulation (weights as A-operand, G = H^T as B-operand).
//   G' = Wcat^T . [G ; Stil (x) 1] + b (x) 1,   Stil = S/64
//   Stil' = Stil . Wsum + b  (linear recursion, computed via MFMA, written to
//   LDS EARLY so the next layer's Sf read is off the critical path)
// dec: no atomics -> fp32 partials [16][8192][32] + reduce kernel; K-split 16.

#define BATCHN 8192

typedef __attribute__((ext_vector_type(8))) short short8;   // 8 bf16
typedef __attribute__((ext_vector_type(4))) float floatx4;  // MFMA acc

__device__ __forceinline__ unsigned short f2b(float f) {
    union { float f; uint32_t u; } v; v.f = f;
    uint32_t r = v.u + 0x7FFFu + ((v.u >> 16) & 1u);
    return (unsigned short)(r >> 16);
}

__device__ __forceinline__ uint32_t pk2(float x, float y) {
    float2 t; t.x = x; t.y = y;
    __hip_bfloat162 h = __float22bfloat162_rn(t);
    union { __hip_bfloat162 h; uint32_t u; } c; c.h = h;
    return c.u;
}

// ---- ws layout ----
#define U16_WENC 0         // WencT [64 f][128 k]
#define U16_WCAT 8192      // WcatT [4 l][64 f][128 k]
#define U16_WSUM 40960     // WsumT [4 l][64 f][64 k]
#define U16_WDEC 57344     // WdecT [32 n][4096 k]
#define U16_H4   188416    // H4    [8192][4096]
#define F32_PART 16871424  // partials [16][8192][32] fp32 (byte off 67485696)

// ---------------- prep: transpose + bf16-convert weights ----------------
__global__ __launch_bounds__(256) void prep_kernel(
    const float* __restrict__ Wenc,
    const float* __restrict__ W1, const float* __restrict__ W2,
    const float* __restrict__ W3, const float* __restrict__ W4,
    const float* __restrict__ Wdec,
    unsigned short* __restrict__ ws)
{
    int tid = blockIdx.x * 256 + threadIdx.x;   // grid covers exactly 188416
    const float* WL[4] = {W1, W2, W3, W4};
    if (tid < 8192) {
        int n = tid >> 7, k = tid & 127;
        ws[U16_WENC + n*128 + k] = f2b(Wenc[k*64 + n]);
    } else if (tid < 40960) {
        int e = tid - 8192;
        int l = e >> 13, r = e & 8191;
        int n = r >> 7, k = r & 127;
        const float* W = WL[l];
        float v = W[k*64 + n];                       // k<64: Wtop, k>=64: Wbot
        if (k < 64) v -= W[(k+64)*64 + n] * (1.0f/64.0f);
        ws[U16_WCAT + l*8192 + n*128 + k] = f2b(v);
    } else if (tid < 57344) {
        int e = tid - 40960;
        int l = e >> 12, r = e & 4095;
        int f = r >> 6, k = r & 63;
        const float* W = WL[l];
        float v = W[k*64 + f] + W[(k+64)*64 + f] * (63.0f/64.0f);
        ws[U16_WSUM + l*4096 + f*64 + k] = f2b(v);
    } else {
        int e = tid - 57344;                         // 0..131071
        int n = e >> 12, k = e & 4095;
        ws[U16_WDEC + n*4096 + k] = f2b(Wdec[k*32 + n]);
    }
}

// ---------------- fused encoder + 4 comm layers (wave-per-sample) ----------------
__global__ __launch_bounds__(256, 3) void fused4_kernel(
    const float* __restrict__ O,
    const unsigned short* __restrict__ WencT,
    const unsigned short* __restrict__ WcatT,
    const unsigned short* __restrict__ WsumT,
    const float* __restrict__ b_enc,
    const float* __restrict__ b1, const float* __restrict__ b2,
    const float* __restrict__ b3, const float* __restrict__ b4,
    unsigned short* __restrict__ H4out)
{
    __shared__ unsigned short sG[4][64*72];   // per-wave G, [agent][feat] pad72
    __shared__ unsigned short sS[4][64];      // per-wave Stil row (bf16)

    const int t = threadIdx.x, lane = t & 63, w = t >> 6;
    const int m = lane & 15, q = lane >> 4;
    const int b = blockIdx.x * 4 + w;
    unsigned short* myG = sG[w];
    unsigned short* myS = sS[w];

    floatx4 acc[4][4];   // [ft][at]: G[feat=ft*16+q*4+r][agent=at*16+m]
    floatx4 bb[4];

    // ---- encoder: G0 = sigmoid(Wenc^T . O^T + b (x) 1), K=128 ----
    #pragma unroll
    for (int ft = 0; ft < 4; ft++) {
        float4 bv = *(const float4*)(b_enc + ft*16 + q*4);
        bb[ft] = (floatx4){bv.x, bv.y, bv.z, bv.w};
    }
    #pragma unroll
    for (int ft = 0; ft < 4; ft++)
        #pragma unroll
        for (int at = 0; at < 4; at++)
            acc[ft][at] = bb[ft];

    const float* Ob = O + (size_t)b * 8192;
    // 2-stage pipeline on O loads: load s+1 while converting/MFMAing s
    float4 stg[2][4][2];
    #pragma unroll
    for (int at = 0; at < 4; at++) {
        const float* pr = Ob + (at*16+m)*128 + q*8;
        stg[0][at][0] = *(const float4*)pr;
        stg[0][at][1] = *(const float4*)(pr + 4);
    }
    #pragma unroll
    for (int s = 0; s < 4; s++) {
        if (s < 3) {
            #pragma unroll
            for (int at = 0; at < 4; at++) {
                const float* pr = Ob + (at*16+m)*128 + (s+1)*32 + q*8;
                stg[(s+1)&1][at][0] = *(const float4*)pr;
                stg[(s+1)&1][at][1] = *(const float4*)(pr + 4);
            }
        }
        short8 Wf[4], Bf[4];
        #pragma unroll
        for (int ft = 0; ft < 4; ft++)
            Wf[ft] = *(const short8*)(WencT + (ft*16+m)*128 + s*32 + q*8);
        #pragma unroll
        for (int at = 0; at < 4; at++) {
            float4 f0 = stg[s&1][at][0], f1 = stg[s&1][at][1];
            uint32_t* pa = (uint32_t*)&Bf[at];
            pa[0] = pk2(f0.x, f0.y); pa[1] = pk2(f0.z, f0.w);
            pa[2] = pk2(f1.x, f1.y); pa[3] = pk2(f1.z, f1.w);
        }
        #pragma unroll
        for (int ft = 0; ft < 4; ft++)
            #pragma unroll
            for (int at = 0; at < 4; at++)
                acc[ft][at] = __builtin_amdgcn_mfma_f32_16x16x32_bf16(Wf[ft], Bf[at], acc[ft][at], 0, 0, 0);
    }
    #pragma unroll
    for (int ft = 0; ft < 4; ft++)
        #pragma unroll
        for (int at = 0; at < 4; at++)
            #pragma unroll
            for (int r = 0; r < 4; r++)
                acc[ft][at][r] = 1.0f / (1.0f + __expf(-acc[ft][at][r]));

    // ---- S0 butterfly (once; sigmoid is the only nonlinearity) ----
    #pragma unroll
    for (int ft = 0; ft < 4; ft++) {
        float tr[4];
        #pragma unroll
        for (int r = 0; r < 4; r++)
            tr[r] = acc[ft][0][r] + acc[ft][1][r] + acc[ft][2][r] + acc[ft][3][r];
        #pragma unroll
        for (int msk = 1; msk <= 8; msk <<= 1)
            #pragma unroll
            for (int r = 0; r < 4; r++)
                tr[r] += __shfl_xor(tr[r], msk, 64);
        uint2 d;
        d.x = pk2(tr[0] * (1.0f/64.0f), tr[1] * (1.0f/64.0f));
        d.y = pk2(tr[2] * (1.0f/64.0f), tr[3] * (1.0f/64.0f));
        if (m == 0) *(uint2*)&myS[ft*16 + q*4] = d;
    }
    // ---- G0 -> LDS [agent][feat] ----
    #pragma unroll
    for (int ft = 0; ft < 4; ft++)
        #pragma unroll
        for (int at = 0; at < 4; at++) {
            uint2 d;
            d.x = pk2(acc[ft][at][0], acc[ft][at][1]);
            d.y = pk2(acc[ft][at][2], acc[ft][at][3]);
            *(uint2*)&myG[(at*16+m)*72 + ft*16 + q*4] = d;
        }

    // ---- 4 comm layers ----
    const float* bs_[4] = {b1, b2, b3, b4};
    #pragma unroll
    for (int l = 0; l < 4; l++) {
        const unsigned short* Wl  = WcatT + l*8192;
        const unsigned short* Wsl = WsumT + l*4096;
        const float* bp = bs_[l];
        #pragma unroll
        for (int ft = 0; ft < 4; ft++) {
            float4 bv = *(const float4*)(bp + ft*16 + q*4);
            bb[ft] = (floatx4){bv.x, bv.y, bv.z, bv.w};
        }
        // Sf/Gf reads first (Gf has the RAW dependency on previous epilogue)
        short8 Sf[2];
        #pragma unroll
        for (int s2 = 0; s2 < 2; s2++)
            Sf[s2] = *(const short8*)&myS[s2*32 + q*8];
        short8 Gf[2][4];
        #pragma unroll
        for (int s2 = 0; s2 < 2; s2++)
            #pragma unroll
            for (int at = 0; at < 4; at++)
                Gf[s2][at] = *(const short8*)&myG[(at*16+m)*72 + s2*32 + q*8];

        // all weight loads issued up front (L1-hot, overlap with MFMAs below)
        short8 Wk[4][4];   // [s: 0,1 = k-lo; 2,3 = k-hi][ft]
        #pragma unroll
        for (int s = 0; s < 4; s++)
            #pragma unroll
            for (int ft = 0; ft < 4; ft++)
                Wk[s][ft] = *(const short8*)(Wl + (ft*16+m)*128 + s*32 + q*8);

        // ---- Stil recursion FIRST; write myS early (off critical path) ----
        if (l < 3) {
            floatx4 sacc[4];
            #pragma unroll
            for (int ft = 0; ft < 4; ft++) sacc[ft] = bb[ft];
            #pragma unroll
            for (int s2 = 0; s2 < 2; s2++)
                #pragma unroll
                for (int ft = 0; ft < 4; ft++) {
                    short8 Wsf = *(const short8*)(Wsl + (ft*16+m)*64 + s2*32 + q*8);
                    sacc[ft] = __builtin_amdgcn_mfma_f32_16x16x32_bf16(Wsf, Sf[s2], sacc[ft], 0, 0, 0);
                }
            #pragma unroll
            for (int ft = 0; ft < 4; ft++) {
                uint2 d;
                d.x = pk2(sacc[ft][0], sacc[ft][1]);
                d.y = pk2(sacc[ft][2], sacc[ft][3]);
                if (m == 0) *(uint2*)&myS[ft*16 + q*4] = d;
            }
        }

        // ---- main MFMAs ----
        #pragma unroll
        for (int ft = 0; ft < 4; ft++)
            #pragma unroll
            for (int at = 0; at < 4; at++)
                acc[ft][at] = bb[ft];
        #pragma unroll
        for (int s2 = 0; s2 < 2; s2++)
            #pragma unroll
            for (int ft = 0; ft < 4; ft++)
                #pragma unroll
                for (int at = 0; at < 4; at++)
                    acc[ft][at] = __builtin_amdgcn_mfma_f32_16x16x32_bf16(Wk[s2][ft], Gf[s2][at], acc[ft][at], 0, 0, 0);
        #pragma unroll
        for (int s2 = 0; s2 < 2; s2++)
            #pragma unroll
            for (int ft = 0; ft < 4; ft++)
                #pragma unroll
                for (int at = 0; at < 4; at++)
                    acc[ft][at] = __builtin_amdgcn_mfma_f32_16x16x32_bf16(Wk[2+s2][ft], Sf[s2], acc[ft][at], 0, 0, 0);

        if (l < 3) {
            #pragma unroll
            for (int ft = 0; ft < 4; ft++)
                #pragma unroll
                for (int at = 0; at < 4; at++) {
                    uint2 d;
                    d.x = pk2(acc[ft][at][0], acc[ft][at][1]);
                    d.y = pk2(acc[ft][at][2], acc[ft][at][3]);
                    *(uint2*)&myG[(at*16+m)*72 + ft*16 + q*4] = d;
                }
        } else {
            unsigned short* Hb = H4out + (size_t)b * 4096;
            #pragma unroll
            for (int ft = 0; ft < 4; ft++)
                #pragma unroll
                for (int at = 0; at < 4; at++) {
                    uint2 d;
                    d.x = pk2(acc[ft][at][0], acc[ft][at][1]);
                    d.y = pk2(acc[ft][at][2], acc[ft][at][3]);
                    *(uint2*)(Hb + (at*16+m)*64 + ft*16 + q*4) = d;
                }
        }
    }
}

// ---------------- decoder: partials, no atomics ----------------
// M=8192, N=32, K=4096; K-split x16 -> P[kc][row][n] fp32.
__global__ __launch_bounds__(256, 4) void dec_kernel(
    const unsigned short* __restrict__ Hf,     // [8192][4096] bf16
    const unsigned short* __restrict__ WdecT,  // [32][4096] bf16
    float* __restrict__ P)                     // [16][8192][32] fp32
{
    int gt = blockIdx.x * 256 + threadIdx.x;
    int wave = gt >> 6;          // 0..8191
    int lane = gt & 63;
    int rb = wave >> 4;          // rows [rb*16, +16)
    int kc = wave & 15;          // K chunk [kc*256, +256)
    int m = lane & 15, q = lane >> 4;

    const unsigned short* aP  = Hf    + (size_t)(rb*16 + m)*4096 + kc*256 + q*8;
    const unsigned short* bP0 = WdecT + (size_t)m*4096        + kc*256 + q*8;
    const unsigned short* bP1 = WdecT + (size_t)(16 + m)*4096 + kc*256 + q*8;

    floatx4 a0 = {0.f, 0.f, 0.f, 0.f}, a1 = {0.f, 0.f, 0.f, 0.f};
    #pragma unroll
    for (int s = 0; s < 8; s++) {
        short8 av  = *(const short8*)(aP  + s*32);
        short8 b0v = *(const short8*)(bP0 + s*32);
        short8 b1v = *(const short8*)(bP1 + s*32);
        a0 = __builtin_amdgcn_mfma_f32_16x16x32_bf16(av, b0v, a0, 0, 0, 0);
        a1 = __builtin_amdgcn_mfma_f32_16x16x32_bf16(av, b1v, a1, 0, 0, 0);
    }
    float* Pk = P + (size_t)kc * (8192*32);
    #pragma unroll
    for (int r = 0; r < 4; r++) {
        int row = rb*16 + q*4 + r;
        Pk[row*32 + m]      = a0[r];
        Pk[row*32 + 16 + m] = a1[r];
    }
}

// ---------------- reduce: out = sum_kc P + b_dec ----------------
__global__ __launch_bounds__(256) void red_kernel(
    const float* __restrict__ P, const float* __restrict__ b_dec,
    float* __restrict__ out)
{
    int tid = blockIdx.x * 256 + threadIdx.x;   // 65536 threads x float4
    float4 bv = *(const float4*)(b_dec + (tid & 7) * 4);
    float4 s = bv;
    #pragma unroll
    for (int kc = 0; kc < 16; kc++) {
        float4 v = *(const float4*)(P + (size_t)kc * (8192*32) + tid*4);
        s.x += v.x; s.y += v.y; s.z += v.z; s.w += v.w;
    }
    *(float4*)(out + tid*4) = s;
}

extern "C" void kernel_launch(void* const* d_in, const int* in_sizes, int n_in,
                              void* d_out, int out_size, void* d_ws, size_t ws_size,
                              hipStream_t stream)
{
    const float* O    = (const float*)d_in[0];
    const float* Wenc = (const float*)d_in[1];
    const float* benc = (const float*)d_in[2];
    const float* W1   = (const float*)d_in[3];
    const float* b1   = (const float*)d_in[4];
    const float* W2   = (const float*)d_in[5];
    const float* b2   = (const float*)d_in[6];
    const float* W3   = (const float*)d_in[7];
    const float* b3   = (const float*)d_in[8];
    const float* W4   = (const float*)d_in[9];
    const float* b4   = (const float*)d_in[10];
    const float* Wdec = (const float*)d_in[11];
    const float* bdec = (const float*)d_in[12];
    float* out = (float*)d_out;
    unsigned short* ws = (unsigned short*)d_ws;
    float* wsf = (float*)d_ws;

    prep_kernel<<<736, 256, 0, stream>>>(Wenc, W1, W2, W3, W4, Wdec, ws);
    fused4_kernel<<<2048, 256, 0, stream>>>(O, ws + U16_WENC, ws + U16_WCAT,
                                            ws + U16_WSUM,
                                            benc, b1, b2, b3, b4, ws + U16_H4);
    dec_kernel<<<2048, 256, 0, stream>>>(ws + U16_H4, ws + U16_WDEC, wsf + F32_PART);
    red_kernel<<<256, 256, 0, stream>>>(wsf + F32_PART, bdec, out);
}